// Round 10
// baseline (30.581 us; speedup 1.0000x reference)
//
#include <hip/hip_runtime.h>
#include <math.h>

#define C_ELEC 322.0637f
#define TILE 64
#define CMAX 4
#define BMAX 256   // max per-pose block count staged in LDS

// ---------------------------------------------------------------------------
// Fused pair kernel: one 64x64 upper-triangular tile pair per workgroup.
// Round 10: reduce kernel replaced by memset(out,0) + per-block fp atomicAdd
// (1200 atomics onto P=4 floats; rounds 2/4 "atomic regressions" were
// confounded with threadfence-last-block / divergent-compaction costs).
//   pre-barrier : coords loads issued; block-id scatter maps; off/btype LDS
//   barrier A   ; atom records (t<128)
//   barrier B   ; cheap d2/validity filter -> LDS survivor queue
//   barrier C   ; all 256 threads process ~4.5% survivors (tables via L2)
//   barrier D   ; cross-wave reduction, one atomicAdd(out[p]) per block
// ---------------------------------------------------------------------------
__global__ void __launch_bounds__(256)
pair_kernel(const float* __restrict__ coords,
            const int* __restrict__ offsets,         // P*B
            const int* __restrict__ block_types,     // P*B
            const int* __restrict__ inter_bondsep,   // P*B*B*C*C
            const int* __restrict__ bt_n_atoms,      // NBT
            const float* __restrict__ bt_pc,         // NBT*APB
            const int* __restrict__ bt_ipd,          // NBT*C*APB
            const int* __restrict__ bt_xpd,          // NBT*APB*APB
            const float* __restrict__ gp,
            float* __restrict__ out,
            int P, int A, int B, int NBT, int APB, int C, int nt, int TP)
{
    __shared__ float4 s_posi[TILE], s_posj[TILE];
    __shared__ int4 s_meti[TILE], s_metj[TILE];
    __shared__ unsigned short s_list[TILE * TILE];   // survivor queue
    __shared__ int s_off[BMAX];
    __shared__ int s_btype[BMAX];
    __shared__ unsigned short s_blki[TILE], s_blkj[TILE];  // block-id maps
    __shared__ int s_cnt;
    __shared__ float s_red[4];

    int bid = blockIdx.x;
    int p = bid / TP;
    int tp = bid - p * TP;
    int ti = 0, rem = tp;
    while (rem >= nt - ti) { rem -= nt - ti; ++ti; }
    int tj = ti + rem;
    int t = threadIdx.x;
    int ibase = ti * TILE, jbase = tj * TILE;
    bool diag = (ti == tj);
    bool bLds = (B <= BMAX);
    size_t pB = (size_t)p * B;
    int APB2 = APB * APB;
    int Cc = C > CMAX ? CMAX : C;

    // ---- pre-barrier: issue coords loads early (hide under scatter) ----
    int local = t & (TILE - 1);
    int aMine = (t < TILE ? ibase : jbase) + local;   // meaningful for t<128
    float cx = 1e9f, cyv = 1e9f, cz = 1e9f;
    if (t < 2 * TILE && aMine < A) {
        const float* cp = coords + ((size_t)p * A + aMine) * 3;
        cx = cp[0]; cyv = cp[1]; cz = cp[2];
    }
    float D = gp[0], D0 = gp[1], S = gp[2], min_dis = gp[3], max_dis = gp[4];

    if (t == 0) s_cnt = 0;

    // ---- pre-barrier: block-id scatter + off/btype staging ----
    if (bLds) {
        for (int b = t; b < B; b += 256) {
            int ob = offsets[pB + b];
            int oe = (b == B - 1) ? 0x7fffffff : offsets[pB + b + 1];
            s_off[b] = ob;
            s_btype[b] = block_types[pB + b];
            int st = (b == 0) ? 0 : ob;    // searchsorted clip-to-0 semantics
            int lo = st > ibase ? st : ibase;
            int hi = oe < ibase + TILE ? oe : ibase + TILE;
            for (int a = lo; a < hi; ++a) s_blki[a - ibase] = (unsigned short)b;
            lo = st > jbase ? st : jbase;
            hi = oe < jbase + TILE ? oe : jbase + TILE;
            for (int a = lo; a < hi; ++a) s_blkj[a - jbase] = (unsigned short)b;
        }
    } else if (t < 2 * TILE) {
        // rare fallback (B > BMAX): per-thread binary search over global offsets
        const int* off = offsets + pB;
        int blk;
        if (aMine >= A) blk = B - 1;
        else {
            int lo = 0, hi2 = B;
            while (lo < hi2) { int mid = (lo + hi2) >> 1; if (off[mid] <= aMine) lo = mid + 1; else hi2 = mid; }
            blk = lo - 1; blk = blk < 0 ? 0 : (blk > B - 1 ? B - 1 : blk);
        }
        if (t < TILE) s_blki[local] = (unsigned short)blk;
        else          s_blkj[local] = (unsigned short)blk;
    }
    __syncthreads();   // A: maps, s_off/s_btype, s_cnt ready

    // ---- atom records (t<128) ----
    if (t < 2 * TILE) {
        float4 pr; int4 mr;
        if (aMine >= A) {
            pr = make_float4(1e9f, 1e9f, 1e9f, 0.f);
            mr = make_int4(B - 1, 0, 0, 0);
        } else {
            int blk = (t < TILE) ? (int)s_blki[local] : (int)s_blkj[local];
            int ob = bLds ? s_off[blk] : offsets[pB + blk];
            int bt = bLds ? s_btype[blk] : block_types[pB + blk];
            bt = bt < 0 ? 0 : (bt >= NBT ? NBT - 1 : bt);
            int aw = aMine - ob;
            int awc = aw < 0 ? 0 : (aw >= APB ? APB - 1 : aw);   // JAX clamps OOB
            float q = bt_pc[(size_t)bt * APB + awc];
            int valid = (aw < bt_n_atoms[bt]) ? 1 : 0;
            int packed = 0;
            for (int c = 0; c < Cc; ++c)
                packed |= (bt_ipd[((size_t)bt * C + c) * APB + awc] & 0xff) << (8 * c);
            pr = make_float4(cx, cyv, cz, valid ? q : 0.f);
            mr = make_int4(blk, bt, awc, packed);
        }
        if (t < TILE) { s_posi[local] = pr; s_meti[local] = mr; }
        else          { s_posj[local] = pr; s_metj[local] = mr; }
    }
    __syncthreads();   // B: records ready

    float max2 = max_dis * max_dis;
    float xm = max_dis * S;
    float esm = D - 0.5f * (D - D0) * (2.f + 2.f * xm + xm * xm) * __expf(-xm);
    float shift = 1.f / (max_dis * esm);

    // ---- filter: cheap d2/validity, survivors -> LDS queue ----
    int jj = local;
    int lo16 = (t >> 6) * 16;
    float4 pj = s_posj[jj];
    if (pj.w != 0.f) {
        for (int k = 0; k < 16; ++k) {
            int ii = lo16 + k;
            float4 pi = s_posi[ii];                 // broadcast, conflict-free
            float dx = pi.x - pj.x, dy = pi.y - pj.y, dz = pi.z - pj.z;
            float d2 = dx * dx + dy * dy + dz * dz;
            bool ok = (d2 < max2) && (pi.w != 0.f);
            if (diag) ok = ok && (ii < jj);
            if (ok) {
                int slot = atomicAdd(&s_cnt, 1);
                s_list[slot] = (unsigned short)(ii | (jj << 6));
            }
        }
    }
    __syncthreads();   // C
    int cnt = s_cnt;

    // ---- process survivors at full lane occupancy (tables direct via L2) ----
    float acc = 0.f;
    for (int e = t; e < cnt; e += 256) {
        int ent = s_list[e];
        int ii = ent & 63, j2 = ent >> 6;
        float4 pi = s_posi[ii];
        float4 pjv = s_posj[j2];
        float dx = pi.x - pjv.x, dy = pi.y - pjv.y, dz = pi.z - pjv.z;
        float d2 = dx * dx + dy * dy + dz * dz;
        int4 mi = s_meti[ii];
        int4 mjv = s_metj[j2];
        int bi = mi.x, bj = mjv.x;
        int bpl;
        if (bi == bj) {
            bpl = bt_xpd[((size_t)mi.y * APB + mi.z) * APB + mjv.z];   // L2-hot
        } else if (C == 2) {
            int4 b4 = *(const int4*)(inter_bondsep +
                           (((size_t)p * B + bi) * B + bj) * 4);        // L2-hot
            int di0 = mi.w & 0xff, di1 = (mi.w >> 8) & 0xff;
            int dj0 = mjv.w & 0xff, dj1 = (mjv.w >> 8) & 0xff;
            bpl = min(min(di0 + b4.x + dj0, di0 + b4.y + dj1),
                      min(di1 + b4.z + dj0, di1 + b4.w + dj1));
        } else {
            const int* ib = inter_bondsep + (((size_t)p * B + bi) * B + bj) * C * C;
            int best = 0x7fffffff;
            for (int c1 = 0; c1 < Cc; ++c1) {
                int dic = (mi.w >> (8 * c1)) & 0xff;
                for (int c2 = 0; c2 < Cc; ++c2) {
                    int v = dic + ib[c1 * C + c2] + ((mjv.w >> (8 * c2)) & 0xff);
                    best = v < best ? v : best;
                }
            }
            bpl = best;
        }
        if (bpl < 4) continue;
        float cpv = bpl > 4 ? 1.f : 0.2f;
        float dist = sqrtf(fmaxf(d2, 1e-12f));
        float dc = fmaxf(dist, min_dis);            // dist < max_dis by filter
        float xs = dc * S;
        float es = D - 0.5f * (D - D0) * (2.f + 2.f * xs + xs * xs) * __expf(-xs);
        acc += C_ELEC * pi.w * pjv.w * (1.f / (dc * es) - shift) * cpv;
    }

    for (int off = 32; off; off >>= 1) acc += __shfl_down(acc, off, 64);
    if ((t & 63) == 0) s_red[t >> 6] = acc;
    __syncthreads();   // D
    if (t == 0)
        atomicAdd(&out[p], s_red[0] + s_red[1] + s_red[2] + s_red[3]);
}

extern "C" void kernel_launch(void* const* d_in, const int* in_sizes, int n_in,
                              void* d_out, int out_size, void* d_ws, size_t ws_size,
                              hipStream_t stream) {
    const float* coords        = (const float*)d_in[0];
    const int*   offsets       = (const int*)d_in[1];
    const int*   block_types   = (const int*)d_in[2];
    const int*   inter_bondsep = (const int*)d_in[4];
    const int*   bt_n_atoms    = (const int*)d_in[5];
    const float* bt_pc         = (const float*)d_in[6];
    const int*   bt_ipd        = (const int*)d_in[9];
    const int*   bt_xpd        = (const int*)d_in[10];
    const float* gp            = (const float*)d_in[11];

    int NBT = in_sizes[5];
    int APB = in_sizes[6] / NBT;
    int PB  = in_sizes[1];
    int B   = in_sizes[3] / PB;
    int P   = PB / B;
    int A   = in_sizes[0] / (3 * P);
    int C2  = in_sizes[4] / in_sizes[3];
    int C   = 1;
    while (C * C < C2) ++C;

    int nt = (A + TILE - 1) / TILE;
    int TP = nt * (nt + 1) / 2;

    // zero the P output floats (graph memset node), then accumulate atomically
    hipMemsetAsync(d_out, 0, (size_t)out_size * sizeof(float), stream);
    hipLaunchKernelGGL(pair_kernel, dim3(P * TP), dim3(256), 0, stream,
                       coords, offsets, block_types, inter_bondsep, bt_n_atoms,
                       bt_pc, bt_ipd, bt_xpd, gp, (float*)d_out,
                       P, A, B, NBT, APB, C, nt, TP);
}

// Round 11
// 14.986 us; speedup vs baseline: 2.0406x; 2.0406x over previous
//
#include <hip/hip_runtime.h>
#include <math.h>

#define C_ELEC 322.0637f
#define TILE 64
#define CMAX 4
#define BMAX 256   // max per-pose block count staged in LDS

// ---------------------------------------------------------------------------
// Fused pair kernel: one 64x64 upper-triangular tile pair per workgroup.
// Best-measured configuration (round 9, 15.2 us). No LDS table staging
// (tables are L2-hot and touched only by ~4.5% survivors); partials + tiny
// reduce kernel (device-scope contended atomics cost ~15 us: rounds 4/10).
//   pre-barrier : coords loads issued; block-id scatter maps; off/btype LDS
//   barrier A   ; atom records (t<128)
//   barrier B   ; cheap d2/validity filter -> LDS survivor queue
//   barrier C   ; all 256 threads process ~4.5% survivors (tables via L2)
//   barrier D   ; cross-wave reduction, write partials[bid]
// ---------------------------------------------------------------------------
__global__ void __launch_bounds__(256)
pair_kernel(const float* __restrict__ coords,
            const int* __restrict__ offsets,         // P*B
            const int* __restrict__ block_types,     // P*B
            const int* __restrict__ inter_bondsep,   // P*B*B*C*C
            const int* __restrict__ bt_n_atoms,      // NBT
            const float* __restrict__ bt_pc,         // NBT*APB
            const int* __restrict__ bt_ipd,          // NBT*C*APB
            const int* __restrict__ bt_xpd,          // NBT*APB*APB
            const float* __restrict__ gp,
            float* __restrict__ partials,
            int P, int A, int B, int NBT, int APB, int C, int nt, int TP)
{
    __shared__ float4 s_posi[TILE], s_posj[TILE];
    __shared__ int4 s_meti[TILE], s_metj[TILE];
    __shared__ unsigned short s_list[TILE * TILE];   // survivor queue
    __shared__ int s_off[BMAX];
    __shared__ int s_btype[BMAX];
    __shared__ unsigned short s_blki[TILE], s_blkj[TILE];  // block-id maps
    __shared__ int s_cnt;
    __shared__ float s_red[4];

    int bid = blockIdx.x;
    int p = bid / TP;
    int tp = bid - p * TP;
    int ti = 0, rem = tp;
    while (rem >= nt - ti) { rem -= nt - ti; ++ti; }
    int tj = ti + rem;
    int t = threadIdx.x;
    int ibase = ti * TILE, jbase = tj * TILE;
    bool diag = (ti == tj);
    bool bLds = (B <= BMAX);
    size_t pB = (size_t)p * B;
    int APB2 = APB * APB;
    int Cc = C > CMAX ? CMAX : C;

    // ---- pre-barrier: issue coords loads early (hide under scatter) ----
    int local = t & (TILE - 1);
    int aMine = (t < TILE ? ibase : jbase) + local;   // meaningful for t<128
    float cx = 1e9f, cyv = 1e9f, cz = 1e9f;
    if (t < 2 * TILE && aMine < A) {
        const float* cp = coords + ((size_t)p * A + aMine) * 3;
        cx = cp[0]; cyv = cp[1]; cz = cp[2];
    }
    float D = gp[0], D0 = gp[1], S = gp[2], min_dis = gp[3], max_dis = gp[4];

    if (t == 0) s_cnt = 0;

    // ---- pre-barrier: block-id scatter + off/btype staging ----
    if (bLds) {
        for (int b = t; b < B; b += 256) {
            int ob = offsets[pB + b];
            int oe = (b == B - 1) ? 0x7fffffff : offsets[pB + b + 1];
            s_off[b] = ob;
            s_btype[b] = block_types[pB + b];
            int st = (b == 0) ? 0 : ob;    // searchsorted clip-to-0 semantics
            int lo = st > ibase ? st : ibase;
            int hi = oe < ibase + TILE ? oe : ibase + TILE;
            for (int a = lo; a < hi; ++a) s_blki[a - ibase] = (unsigned short)b;
            lo = st > jbase ? st : jbase;
            hi = oe < jbase + TILE ? oe : jbase + TILE;
            for (int a = lo; a < hi; ++a) s_blkj[a - jbase] = (unsigned short)b;
        }
    } else if (t < 2 * TILE) {
        // rare fallback (B > BMAX): per-thread binary search over global offsets
        const int* off = offsets + pB;
        int blk;
        if (aMine >= A) blk = B - 1;
        else {
            int lo = 0, hi2 = B;
            while (lo < hi2) { int mid = (lo + hi2) >> 1; if (off[mid] <= aMine) lo = mid + 1; else hi2 = mid; }
            blk = lo - 1; blk = blk < 0 ? 0 : (blk > B - 1 ? B - 1 : blk);
        }
        if (t < TILE) s_blki[local] = (unsigned short)blk;
        else          s_blkj[local] = (unsigned short)blk;
    }
    __syncthreads();   // A: maps, s_off/s_btype, s_cnt ready

    // ---- atom records (t<128) ----
    if (t < 2 * TILE) {
        float4 pr; int4 mr;
        if (aMine >= A) {
            pr = make_float4(1e9f, 1e9f, 1e9f, 0.f);
            mr = make_int4(B - 1, 0, 0, 0);
        } else {
            int blk = (t < TILE) ? (int)s_blki[local] : (int)s_blkj[local];
            int ob = bLds ? s_off[blk] : offsets[pB + blk];
            int bt = bLds ? s_btype[blk] : block_types[pB + blk];
            bt = bt < 0 ? 0 : (bt >= NBT ? NBT - 1 : bt);
            int aw = aMine - ob;
            int awc = aw < 0 ? 0 : (aw >= APB ? APB - 1 : aw);   // JAX clamps OOB
            float q = bt_pc[(size_t)bt * APB + awc];
            int valid = (aw < bt_n_atoms[bt]) ? 1 : 0;
            int packed = 0;
            for (int c = 0; c < Cc; ++c)
                packed |= (bt_ipd[((size_t)bt * C + c) * APB + awc] & 0xff) << (8 * c);
            pr = make_float4(cx, cyv, cz, valid ? q : 0.f);
            mr = make_int4(blk, bt, awc, packed);
        }
        if (t < TILE) { s_posi[local] = pr; s_meti[local] = mr; }
        else          { s_posj[local] = pr; s_metj[local] = mr; }
    }
    __syncthreads();   // B: records ready

    float max2 = max_dis * max_dis;
    float xm = max_dis * S;
    float esm = D - 0.5f * (D - D0) * (2.f + 2.f * xm + xm * xm) * __expf(-xm);
    float shift = 1.f / (max_dis * esm);

    // ---- filter: cheap d2/validity, survivors -> LDS queue ----
    int jj = local;
    int lo16 = (t >> 6) * 16;
    float4 pj = s_posj[jj];
    if (pj.w != 0.f) {
        for (int k = 0; k < 16; ++k) {
            int ii = lo16 + k;
            float4 pi = s_posi[ii];                 // broadcast, conflict-free
            float dx = pi.x - pj.x, dy = pi.y - pj.y, dz = pi.z - pj.z;
            float d2 = dx * dx + dy * dy + dz * dz;
            bool ok = (d2 < max2) && (pi.w != 0.f);
            if (diag) ok = ok && (ii < jj);
            if (ok) {
                int slot = atomicAdd(&s_cnt, 1);
                s_list[slot] = (unsigned short)(ii | (jj << 6));
            }
        }
    }
    __syncthreads();   // C
    int cnt = s_cnt;

    // ---- process survivors at full lane occupancy (tables direct via L2) ----
    float acc = 0.f;
    for (int e = t; e < cnt; e += 256) {
        int ent = s_list[e];
        int ii = ent & 63, j2 = ent >> 6;
        float4 pi = s_posi[ii];
        float4 pjv = s_posj[j2];
        float dx = pi.x - pjv.x, dy = pi.y - pjv.y, dz = pi.z - pjv.z;
        float d2 = dx * dx + dy * dy + dz * dz;
        int4 mi = s_meti[ii];
        int4 mjv = s_metj[j2];
        int bi = mi.x, bj = mjv.x;
        int bpl;
        if (bi == bj) {
            bpl = bt_xpd[((size_t)mi.y * APB + mi.z) * APB + mjv.z];   // L2-hot
        } else if (C == 2) {
            int4 b4 = *(const int4*)(inter_bondsep +
                           (((size_t)p * B + bi) * B + bj) * 4);        // L2-hot
            int di0 = mi.w & 0xff, di1 = (mi.w >> 8) & 0xff;
            int dj0 = mjv.w & 0xff, dj1 = (mjv.w >> 8) & 0xff;
            bpl = min(min(di0 + b4.x + dj0, di0 + b4.y + dj1),
                      min(di1 + b4.z + dj0, di1 + b4.w + dj1));
        } else {
            const int* ib = inter_bondsep + (((size_t)p * B + bi) * B + bj) * C * C;
            int best = 0x7fffffff;
            for (int c1 = 0; c1 < Cc; ++c1) {
                int dic = (mi.w >> (8 * c1)) & 0xff;
                for (int c2 = 0; c2 < Cc; ++c2) {
                    int v = dic + ib[c1 * C + c2] + ((mjv.w >> (8 * c2)) & 0xff);
                    best = v < best ? v : best;
                }
            }
            bpl = best;
        }
        if (bpl < 4) continue;
        float cpv = bpl > 4 ? 1.f : 0.2f;
        float dist = sqrtf(fmaxf(d2, 1e-12f));
        float dc = fmaxf(dist, min_dis);            // dist < max_dis by filter
        float xs = dc * S;
        float es = D - 0.5f * (D - D0) * (2.f + 2.f * xs + xs * xs) * __expf(-xs);
        acc += C_ELEC * pi.w * pjv.w * (1.f / (dc * es) - shift) * cpv;
    }

    for (int off = 32; off; off >>= 1) acc += __shfl_down(acc, off, 64);
    if ((t & 63) == 0) s_red[t >> 6] = acc;
    __syncthreads();   // D
    if (t == 0) partials[bid] = s_red[0] + s_red[1] + s_red[2] + s_red[3];
}

__global__ void __launch_bounds__(256)
reduce_kernel(const float* __restrict__ partials, float* __restrict__ out, int TP)
{
    int p = blockIdx.x;
    float acc = 0.f;
    for (int i = threadIdx.x; i < TP; i += 256) acc += partials[(size_t)p * TP + i];
    for (int off = 32; off; off >>= 1) acc += __shfl_down(acc, off, 64);
    __shared__ float s[4];
    if ((threadIdx.x & 63) == 0) s[threadIdx.x >> 6] = acc;
    __syncthreads();
    if (threadIdx.x == 0) out[p] = s[0] + s[1] + s[2] + s[3];
}

extern "C" void kernel_launch(void* const* d_in, const int* in_sizes, int n_in,
                              void* d_out, int out_size, void* d_ws, size_t ws_size,
                              hipStream_t stream) {
    const float* coords        = (const float*)d_in[0];
    const int*   offsets       = (const int*)d_in[1];
    const int*   block_types   = (const int*)d_in[2];
    const int*   inter_bondsep = (const int*)d_in[4];
    const int*   bt_n_atoms    = (const int*)d_in[5];
    const float* bt_pc         = (const float*)d_in[6];
    const int*   bt_ipd        = (const int*)d_in[9];
    const int*   bt_xpd        = (const int*)d_in[10];
    const float* gp            = (const float*)d_in[11];

    int NBT = in_sizes[5];
    int APB = in_sizes[6] / NBT;
    int PB  = in_sizes[1];
    int B   = in_sizes[3] / PB;
    int P   = PB / B;
    int A   = in_sizes[0] / (3 * P);
    int C2  = in_sizes[4] / in_sizes[3];
    int C   = 1;
    while (C * C < C2) ++C;

    int nt = (A + TILE - 1) / TILE;
    int TP = nt * (nt + 1) / 2;

    float* partials = (float*)d_ws;   // P*TP floats, fully overwritten each call

    hipLaunchKernelGGL(pair_kernel, dim3(P * TP), dim3(256), 0, stream,
                       coords, offsets, block_types, inter_bondsep, bt_n_atoms,
                       bt_pc, bt_ipd, bt_xpd, gp, partials,
                       P, A, B, NBT, APB, C, nt, TP);
    hipLaunchKernelGGL(reduce_kernel, dim3(P), dim3(256), 0, stream,
                       partials, (float*)d_out, TP);
}